// Round 1
// baseline (167.837 us; speedup 1.0000x reference)
//
#include <hip/hip_runtime.h>
#include <hip/hip_bf16.h>

#define D_MODEL 1024
#define NQKV 3072
#define BM 128
#define BN 128
#define BK 32

typedef __attribute__((ext_vector_type(8))) short bf16x8;
typedef __attribute__((ext_vector_type(4))) float f32x4;
typedef __attribute__((ext_vector_type(8))) unsigned short u16x8;

static __device__ __forceinline__ unsigned short f2bf(float f){
  unsigned int x = __float_as_uint(f);
  x += 0x7fff + ((x >> 16) & 1);   // RNE
  return (unsigned short)(x >> 16);
}
static __device__ __forceinline__ float bf2f(unsigned short u){
  return __uint_as_float(((unsigned int)u) << 16);
}

// ---------------- LayerNorm -> bf16 ----------------
__global__ __launch_bounds__(256) void ln_kernel(const float* __restrict__ inp,
    const float* __restrict__ gamma, const float* __restrict__ beta,
    unsigned short* __restrict__ X){
  const int row = blockIdx.x;
  const int t = threadIdx.x;
  const float4* ip = (const float4*)(inp + (size_t)row * D_MODEL);
  float4 v = ip[t];
  float s1 = v.x + v.y + v.z + v.w;
  float s2 = v.x*v.x + v.y*v.y + v.z*v.z + v.w*v.w;
#pragma unroll
  for (int off = 32; off >= 1; off >>= 1){
    s1 += __shfl_down(s1, off);
    s2 += __shfl_down(s2, off);
  }
  __shared__ float red[8];
  const int wave = t >> 6, lane = t & 63;
  if (lane == 0){ red[wave] = s1; red[4 + wave] = s2; }
  __syncthreads();
  s1 = red[0] + red[1] + red[2] + red[3];
  s2 = red[4] + red[5] + red[6] + red[7];
  const float mu   = s1 * (1.0f / D_MODEL);
  const float var  = s2 * (1.0f / D_MODEL) - mu * mu;
  const float rstd = rsqrtf(var + 1e-5f);
  float4 g = ((const float4*)gamma)[t];
  float4 b = ((const float4*)beta)[t];
  ushort4 o;
  o.x = f2bf((v.x - mu) * rstd * g.x + b.x);
  o.y = f2bf((v.y - mu) * rstd * g.y + b.y);
  o.z = f2bf((v.z - mu) * rstd * g.z + b.z);
  o.w = f2bf((v.w - mu) * rstd * g.w + b.w);
  ((ushort4*)(X + (size_t)row * D_MODEL))[t] = o;
}

// ------------- W transpose + fp32->bf16 : Wt[n][k] = W[k][n] -------------
__global__ __launch_bounds__(256) void wtrans_kernel(const float* __restrict__ Wq,
    const float* __restrict__ Wk, const float* __restrict__ Wv,
    unsigned short* __restrict__ Wt){
  __shared__ float tile[32][33];
  const float* W = (blockIdx.z == 0) ? Wq : ((blockIdx.z == 1) ? Wk : Wv);
  const int k0 = blockIdx.x * 32, n0 = blockIdx.y * 32;
  const int r = threadIdx.x >> 5, c = threadIdx.x & 31;
#pragma unroll
  for (int i = 0; i < 4; i++)
    tile[r + i*8][c] = W[(size_t)(k0 + r + i*8) * D_MODEL + n0 + c];
  __syncthreads();
  unsigned short* dst = Wt + (size_t)(blockIdx.z * D_MODEL + n0) * D_MODEL + k0;
#pragma unroll
  for (int i = 0; i < 4; i++){
    int rr = r + i*8;
    dst[(size_t)rr * D_MODEL + c] = f2bf(tile[c][rr]);
  }
}

__global__ void biascat_kernel(const float* __restrict__ bq, const float* __restrict__ bk,
                               const float* __restrict__ bv, float* __restrict__ bc){
  int i = blockIdx.x * 256 + threadIdx.x;
  float v = (i < 1024) ? bq[i] : (i < 2048) ? bk[i - 1024] : bv[i - 2048];
  bc[i] = v;
}

// ---------------- GEMM: QKV[M=8192][N=3072] = Xln @ Wt^T + bias ----------------
// A: [M][1024] bf16 row-major.  Bt: [N][1024] bf16 row-major (K-major).
__global__ __launch_bounds__(256) void gemm_kernel(const unsigned short* __restrict__ A,
    const unsigned short* __restrict__ Bt, const float* __restrict__ bias,
    unsigned short* __restrict__ C){
  __shared__ unsigned short As[BM * BK];
  __shared__ unsigned short Bs[BN * BK];
  const int tid = threadIdx.x;
  const int wave = tid >> 6, lane = tid & 63;
  const int wr = wave >> 1, wc = wave & 1;
  const int lr = lane & 15, kg = lane >> 4;
  const int m0 = blockIdx.x * BM, n0 = blockIdx.y * BN;

  f32x4 acc[4][4] = {};

  for (int k0 = 0; k0 < 1024; k0 += BK){
#pragma unroll
    for (int i = 0; i < 2; i++){
      int s = i * 256 + tid;
      int row = s >> 2, cs = s & 3;
      __builtin_amdgcn_global_load_lds(
        (const __attribute__((address_space(1))) void*)(A + (size_t)(m0 + row) * 1024 + k0 + cs * 8),
        (__attribute__((address_space(3))) void*)(As + s * 8), 16, 0, 0);
      __builtin_amdgcn_global_load_lds(
        (const __attribute__((address_space(1))) void*)(Bt + (size_t)(n0 + row) * 1024 + k0 + cs * 8),
        (__attribute__((address_space(3))) void*)(Bs + s * 8), 16, 0, 0);
    }
    __syncthreads();

    bf16x8 a[4], b[4];
    const bf16x8* Ap = (const bf16x8*)As;
    const bf16x8* Bp = (const bf16x8*)Bs;
#pragma unroll
    for (int m = 0; m < 4; m++) a[m] = Ap[(wr*64 + m*16 + lr) * 4 + kg];
#pragma unroll
    for (int n = 0; n < 4; n++) b[n] = Bp[(wc*64 + n*16 + lr) * 4 + kg];
#pragma unroll
    for (int m = 0; m < 4; m++)
#pragma unroll
      for (int n = 0; n < 4; n++)
        acc[m][n] = __builtin_amdgcn_mfma_f32_16x16x32_bf16(a[m], b[n], acc[m][n], 0, 0, 0);
    __syncthreads();
  }

#pragma unroll
  for (int n = 0; n < 4; n++){
    const int gcol = n0 + wc*64 + n*16 + lr;
    const float bb = bias[gcol];
#pragma unroll
    for (int m = 0; m < 4; m++){
      const int gr = m0 + wr*64 + m*16 + kg*4;
#pragma unroll
      for (int r = 0; r < 4; r++)
        C[(size_t)(gr + r) * NQKV + gcol] = f2bf(acc[m][n][r] + bb);
    }
  }
}

// ---------------- per-token attention + residual ----------------
// one wave per token; lane i owns score row i (i = 0..63)
__global__ __launch_bounds__(256) void attn_kernel(const unsigned short* __restrict__ qkv,
    const float* __restrict__ inp, float* __restrict__ out){
  __shared__ float Ks[4][64][16];
  __shared__ float Vs[4][64][16];
  const int wave = threadIdx.x >> 6, lane = threadIdx.x & 63;
  const int token = blockIdx.x * 4 + wave;
  const unsigned short* row = qkv + (size_t)token * NQKV;

  // stage K row `lane` and V row `lane` (fp32 in LDS)
  const u16x8* kp = (const u16x8*)(row + 1024 + lane * 16);
  u16x8 k0v = kp[0], k1v = kp[1];
  const u16x8* vp = (const u16x8*)(row + 2048 + lane * 16);
  u16x8 v0v = vp[0], v1v = vp[1];
#pragma unroll
  for (int h = 0; h < 8; h++){
    Ks[wave][lane][h]     = bf2f(k0v[h]);
    Ks[wave][lane][h + 8] = bf2f(k1v[h]);
    Vs[wave][lane][h]     = bf2f(v0v[h]);
    Vs[wave][lane][h + 8] = bf2f(v1v[h]);
  }
  // Q row `lane`, pre-scaled by 1/sqrt(64)
  const u16x8* qp = (const u16x8*)(row + lane * 16);
  u16x8 q0v = qp[0], q1v = qp[1];
  float q[16];
#pragma unroll
  for (int h = 0; h < 8; h++){
    q[h]     = bf2f(q0v[h]) * 0.125f;
    q[h + 8] = bf2f(q1v[h]) * 0.125f;
  }
  __syncthreads();

  // scores s[j] = q . K[j]
  float s[64];
#pragma unroll
  for (int j = 0; j < 64; j++){
    const float* kr = &Ks[wave][j][0];
    float acc = 0.0f;
#pragma unroll
    for (int h = 0; h < 16; h++) acc += q[h] * kr[h];
    s[j] = acc;
  }
  // max (4 parallel chains)
  float m0 = s[0], m1 = s[1], m2 = s[2], m3 = s[3];
#pragma unroll
  for (int j = 4; j < 64; j += 4){
    m0 = fmaxf(m0, s[j]); m1 = fmaxf(m1, s[j+1]);
    m2 = fmaxf(m2, s[j+2]); m3 = fmaxf(m3, s[j+3]);
  }
  const float mx = fmaxf(fmaxf(m0, m1), fmaxf(m2, m3));
  // exp + sum (4 parallel chains)
  float a0 = 0, a1 = 0, a2 = 0, a3 = 0;
#pragma unroll
  for (int j = 0; j < 64; j += 4){
    s[j]   = __expf(s[j]   - mx); a0 += s[j];
    s[j+1] = __expf(s[j+1] - mx); a1 += s[j+1];
    s[j+2] = __expf(s[j+2] - mx); a2 += s[j+2];
    s[j+3] = __expf(s[j+3] - mx); a3 += s[j+3];
  }
  const float inv = 1.0f / ((a0 + a1) + (a2 + a3));

  // O[h] = sum_j p_j * V[j][h]
  float o[16];
#pragma unroll
  for (int h = 0; h < 16; h++) o[h] = 0.0f;
#pragma unroll
  for (int j = 0; j < 64; j++){
    const float p = s[j];
    const float* vr = &Vs[wave][j][0];
#pragma unroll
    for (int h = 0; h < 16; h++) o[h] += p * vr[h];
  }

  const float4* ip4 = (const float4*)(inp + (size_t)token * D_MODEL + lane * 16);
  float4* op4 = (float4*)(out + (size_t)token * D_MODEL + lane * 16);
#pragma unroll
  for (int w = 0; w < 4; w++){
    float4 iv = ip4[w];
    float4 ov;
    ov.x = iv.x + o[w*4 + 0] * inv;
    ov.y = iv.y + o[w*4 + 1] * inv;
    ov.z = iv.z + o[w*4 + 2] * inv;
    ov.w = iv.w + o[w*4 + 3] * inv;
    op4[w] = ov;
  }
}

extern "C" void kernel_launch(void* const* d_in, const int* in_sizes, int n_in,
                              void* d_out, int out_size, void* d_ws, size_t ws_size,
                              hipStream_t stream) {
  const float* inp   = (const float*)d_in[0];
  const float* Wq    = (const float*)d_in[1];
  const float* bq    = (const float*)d_in[2];
  const float* Wk    = (const float*)d_in[3];
  const float* bk    = (const float*)d_in[4];
  const float* Wv    = (const float*)d_in[5];
  const float* bv    = (const float*)d_in[6];
  const float* gamma = (const float*)d_in[7];
  const float* beta  = (const float*)d_in[8];
  float* out = (float*)d_out;

  char* ws = (char*)d_ws;
  unsigned short* Xln  = (unsigned short*)ws;                 // 8192*1024*2  = 16,777,216 B
  unsigned short* Wt   = (unsigned short*)(ws + 16777216);    // 3072*1024*2  =  6,291,456 B
  float*          bc   = (float*)(ws + 23068672);             // 3072*4       =     12,288 B
  unsigned short* QKV  = (unsigned short*)(ws + 23080960);    // 8192*3072*2  = 50,331,648 B

  ln_kernel<<<8192, 256, 0, stream>>>(inp, gamma, beta, Xln);
  wtrans_kernel<<<dim3(32, 32, 3), 256, 0, stream>>>(Wq, Wk, Wv, Wt);
  biascat_kernel<<<12, 256, 0, stream>>>(bq, bk, bv, bc);
  gemm_kernel<<<dim3(64, 24), 256, 0, stream>>>(Xln, Wt, bc, QKV);
  attn_kernel<<<2048, 256, 0, stream>>>(QKV, inp, out);
}

// Round 2
// 100.807 us; speedup vs baseline: 1.6649x; 1.6649x over previous
//
#include <hip/hip_runtime.h>
#include <hip/hip_bf16.h>

#define D_MODEL 1024
#define NQKV 3072
#define BM 128
#define BN 128
#define BK 32

typedef __attribute__((ext_vector_type(8))) short bf16x8;
typedef __attribute__((ext_vector_type(4))) float f32x4;
typedef __attribute__((ext_vector_type(16))) float f32x16;
typedef __attribute__((ext_vector_type(8))) unsigned short u16x8;

static __device__ __forceinline__ unsigned short f2bf(float f){
  unsigned int x = __float_as_uint(f);
  x += 0x7fff + ((x >> 16) & 1);   // RNE
  return (unsigned short)(x >> 16);
}
static __device__ __forceinline__ float bf2f(unsigned short u){
  return __uint_as_float(((unsigned int)u) << 16);
}

// ---------------- LayerNorm -> bf16 ----------------
__global__ __launch_bounds__(256) void ln_kernel(const float* __restrict__ inp,
    const float* __restrict__ gamma, const float* __restrict__ beta,
    unsigned short* __restrict__ X){
  const int row = blockIdx.x;
  const int t = threadIdx.x;
  const float4* ip = (const float4*)(inp + (size_t)row * D_MODEL);
  float4 v = ip[t];
  float s1 = v.x + v.y + v.z + v.w;
  float s2 = v.x*v.x + v.y*v.y + v.z*v.z + v.w*v.w;
#pragma unroll
  for (int off = 32; off >= 1; off >>= 1){
    s1 += __shfl_down(s1, off);
    s2 += __shfl_down(s2, off);
  }
  __shared__ float red[8];
  const int wave = t >> 6, lane = t & 63;
  if (lane == 0){ red[wave] = s1; red[4 + wave] = s2; }
  __syncthreads();
  s1 = red[0] + red[1] + red[2] + red[3];
  s2 = red[4] + red[5] + red[6] + red[7];
  const float mu   = s1 * (1.0f / D_MODEL);
  const float var  = s2 * (1.0f / D_MODEL) - mu * mu;
  const float rstd = rsqrtf(var + 1e-5f);
  float4 g = ((const float4*)gamma)[t];
  float4 b = ((const float4*)beta)[t];
  ushort4 o;
  o.x = f2bf((v.x - mu) * rstd * g.x + b.x);
  o.y = f2bf((v.y - mu) * rstd * g.y + b.y);
  o.z = f2bf((v.z - mu) * rstd * g.z + b.z);
  o.w = f2bf((v.w - mu) * rstd * g.w + b.w);
  ((ushort4*)(X + (size_t)row * D_MODEL))[t] = o;
}

// ------------- W transpose + fp32->bf16 : Wt[n][k] = W[k][n] -------------
__global__ __launch_bounds__(256) void wtrans_kernel(const float* __restrict__ Wq,
    const float* __restrict__ Wk, const float* __restrict__ Wv,
    unsigned short* __restrict__ Wt){
  __shared__ float tile[32][33];
  const float* W = (blockIdx.z == 0) ? Wq : ((blockIdx.z == 1) ? Wk : Wv);
  const int k0 = blockIdx.x * 32, n0 = blockIdx.y * 32;
  const int r = threadIdx.x >> 5, c = threadIdx.x & 31;
#pragma unroll
  for (int i = 0; i < 4; i++)
    tile[r + i*8][c] = W[(size_t)(k0 + r + i*8) * D_MODEL + n0 + c];
  __syncthreads();
  unsigned short* dst = Wt + (size_t)(blockIdx.z * D_MODEL + n0) * D_MODEL + k0;
#pragma unroll
  for (int i = 0; i < 4; i++){
    int rr = r + i*8;
    dst[(size_t)rr * D_MODEL + c] = f2bf(tile[c][rr]);
  }
}

__global__ void biascat_kernel(const float* __restrict__ bq, const float* __restrict__ bk,
                               const float* __restrict__ bv, float* __restrict__ bc){
  int i = blockIdx.x * 256 + threadIdx.x;
  float v = (i < 1024) ? bq[i] : (i < 2048) ? bk[i - 1024] : bv[i - 2048];
  bc[i] = v;
}

// ---------------- GEMM: QKV[M=8192][N=3072] = Xln @ Wt^T + bias ----------------
__global__ __launch_bounds__(256) void gemm_kernel(const unsigned short* __restrict__ A,
    const unsigned short* __restrict__ Bt, const float* __restrict__ bias,
    unsigned short* __restrict__ C){
  __shared__ unsigned short As[BM * BK];
  __shared__ unsigned short Bs[BN * BK];
  const int tid = threadIdx.x;
  const int wave = tid >> 6, lane = tid & 63;
  const int wr = wave >> 1, wc = wave & 1;
  const int lr = lane & 15, kg = lane >> 4;
  const int m0 = blockIdx.x * BM, n0 = blockIdx.y * BN;

  f32x4 acc[4][4] = {};

  for (int k0 = 0; k0 < 1024; k0 += BK){
#pragma unroll
    for (int i = 0; i < 2; i++){
      int s = i * 256 + tid;
      int row = s >> 2, cs = s & 3;
      __builtin_amdgcn_global_load_lds(
        (const __attribute__((address_space(1))) void*)(A + (size_t)(m0 + row) * 1024 + k0 + cs * 8),
        (__attribute__((address_space(3))) void*)(As + s * 8), 16, 0, 0);
      __builtin_amdgcn_global_load_lds(
        (const __attribute__((address_space(1))) void*)(Bt + (size_t)(n0 + row) * 1024 + k0 + cs * 8),
        (__attribute__((address_space(3))) void*)(Bs + s * 8), 16, 0, 0);
    }
    __syncthreads();

    bf16x8 a[4], b[4];
    const bf16x8* Ap = (const bf16x8*)As;
    const bf16x8* Bp = (const bf16x8*)Bs;
#pragma unroll
    for (int m = 0; m < 4; m++) a[m] = Ap[(wr*64 + m*16 + lr) * 4 + kg];
#pragma unroll
    for (int n = 0; n < 4; n++) b[n] = Bp[(wc*64 + n*16 + lr) * 4 + kg];
#pragma unroll
    for (int m = 0; m < 4; m++)
#pragma unroll
      for (int n = 0; n < 4; n++)
        acc[m][n] = __builtin_amdgcn_mfma_f32_16x16x32_bf16(a[m], b[n], acc[m][n], 0, 0, 0);
    __syncthreads();
  }

#pragma unroll
  for (int n = 0; n < 4; n++){
    const int gcol = n0 + wc*64 + n*16 + lr;
    const float bb = bias[gcol];
#pragma unroll
    for (int m = 0; m < 4; m++){
      const int gr = m0 + wr*64 + m*16 + kg*4;
#pragma unroll
      for (int r = 0; r < 4; r++)
        C[(size_t)(gr + r) * NQKV + gcol] = f2bf(acc[m][n][r] + bb);
    }
  }
}

// ---------------- per-token attention + residual (MFMA, swapped-QK^T) ----------------
// One wave per token.
//  S^T = K·Q^T via 4x mfma_32x32x16 (K=16 exact). C-layout: col i = ti*32+(l&31),
//  row j = mt*32 + (reg&3)+8*(reg>>2)+4*(l>>5). Softmax lane-local + one shfl_xor(32).
//  P (with 1/sum folded) -> bf16 -> LDS [64][64], XOR-swizzled byte ^= (i&7)<<4.
//  O^T = V^T·P^T via 8x mfma_16x16x32; V^T gathered from global; fused residual.
__global__ __launch_bounds__(256) void attn_kernel(const unsigned short* __restrict__ qkv,
    const float* __restrict__ inp, float* __restrict__ out){
  __shared__ unsigned short P[4][64 * 64];
  const int wave = threadIdx.x >> 6, lane = threadIdx.x & 63;
  const int token = blockIdx.x * 4 + wave;
  const unsigned short* row = qkv + (size_t)token * NQKV;
  const int l31 = lane & 31, hi = lane >> 5;
  const int l15 = lane & 15, qg = lane >> 4;
  char* pbase = (char*)&P[wave][0];

  // --- A/B fragments for S^T = K·Q^T : contiguous 16B loads per lane ---
  bf16x8 kf[2], qf[2];
#pragma unroll
  for (int mt = 0; mt < 2; mt++)
    kf[mt] = *(const bf16x8*)(row + 1024 + (mt*32 + l31)*16 + hi*8);
#pragma unroll
  for (int nt = 0; nt < 2; nt++)
    qf[nt] = *(const bf16x8*)(row + (nt*32 + l31)*16 + hi*8);

  // --- V^T A-fragments for PV: lane holds V[j = kc*32+qg*8+e][h = l15] ---
  bf16x8 vf[2];
#pragma unroll
  for (int kc = 0; kc < 2; kc++)
#pragma unroll
    for (int e = 0; e < 8; e++)
      vf[kc][e] = (short)row[2048 + (kc*32 + qg*8 + e)*16 + l15];

  // --- S^T tiles ---
  f32x16 s[2][2] = {};
#pragma unroll
  for (int mt = 0; mt < 2; mt++)
#pragma unroll
    for (int nt = 0; nt < 2; nt++)
      s[mt][nt] = __builtin_amdgcn_mfma_f32_32x32x16_bf16(kf[mt], qf[nt], s[mt][nt], 0, 0, 0);

  // --- softmax per owned column i = ti*32 + l31 (lane holds 16 j's per mt; other
  //     half of each row lives in lane^32) ---
#pragma unroll
  for (int ti = 0; ti < 2; ti++){
    float m = s[0][ti][0];
#pragma unroll
    for (int mt = 0; mt < 2; mt++)
#pragma unroll
      for (int r = 0; r < 16; r++) m = fmaxf(m, s[mt][ti][r]);
    m = fmaxf(m, __shfl_xor(m, 32));
    float sum = 0.0f;
#pragma unroll
    for (int mt = 0; mt < 2; mt++)
#pragma unroll
      for (int r = 0; r < 16; r++){
        float p = exp2f((s[mt][ti][r] - m) * 0.1803368801f); // 0.125 * log2(e)
        s[mt][ti][r] = p;
        sum += p;
      }
    sum += __shfl_xor(sum, 32);
    const float invs = 1.0f / sum;
    const int i = ti*32 + l31;
    const int sw = (i & 7) << 4;
#pragma unroll
    for (int mt = 0; mt < 2; mt++)
#pragma unroll
      for (int g = 0; g < 4; g++){
        ushort4 pk;
        pk.x = f2bf(s[mt][ti][4*g + 0] * invs);
        pk.y = f2bf(s[mt][ti][4*g + 1] * invs);
        pk.z = f2bf(s[mt][ti][4*g + 2] * invs);
        pk.w = f2bf(s[mt][ti][4*g + 3] * invs);
        const int jbyte = mt*64 + g*16 + hi*8;    // j0 = mt*32 + 8g + 4hi
        *(ushort4*)(pbase + ((i*128 + jbyte) ^ sw)) = pk;
      }
  }
  __syncthreads();   // intra-wave LDS write->read ordering (cheap; waves balanced)

  // --- O^T = V^T · P^T : D[h][i], 4 N-tiles x 2 K-chunks ---
  f32x4 o[4] = {};
#pragma unroll
  for (int nt = 0; nt < 4; nt++){
    const int n = nt*16 + l15;
    const int swr = (n & 7) << 4;
#pragma unroll
    for (int kc = 0; kc < 2; kc++){
      bf16x8 pb = *(const bf16x8*)(pbase + ((n*128 + kc*64 + qg*16) ^ swr));
      o[nt] = __builtin_amdgcn_mfma_f32_16x16x32_bf16(vf[kc], pb, o[nt], 0, 0, 0);
    }
  }

  // --- fused residual epilogue: out[token][i*16+h] = inp + O^T[h][i] ---
  const size_t base = (size_t)token * D_MODEL;
#pragma unroll
  for (int nt = 0; nt < 4; nt++){
    const int i = nt*16 + l15;
    const float4 iv = *(const float4*)(inp + base + i*16 + qg*4);
    float4 ov;
    ov.x = iv.x + o[nt][0];
    ov.y = iv.y + o[nt][1];
    ov.z = iv.z + o[nt][2];
    ov.w = iv.w + o[nt][3];
    *(float4*)(out + base + i*16 + qg*4) = ov;
  }
}

extern "C" void kernel_launch(void* const* d_in, const int* in_sizes, int n_in,
                              void* d_out, int out_size, void* d_ws, size_t ws_size,
                              hipStream_t stream) {
  const float* inp   = (const float*)d_in[0];
  const float* Wq    = (const float*)d_in[1];
  const float* bq    = (const float*)d_in[2];
  const float* Wk    = (const float*)d_in[3];
  const float* bk    = (const float*)d_in[4];
  const float* Wv    = (const float*)d_in[5];
  const float* bv    = (const float*)d_in[6];
  const float* gamma = (const float*)d_in[7];
  const float* beta  = (const float*)d_in[8];
  float* out = (float*)d_out;

  char* ws = (char*)d_ws;
  unsigned short* Xln  = (unsigned short*)ws;                 // 8192*1024*2  = 16,777,216 B
  unsigned short* Wt   = (unsigned short*)(ws + 16777216);    // 3072*1024*2  =  6,291,456 B
  float*          bc   = (float*)(ws + 23068672);             // 3072*4       =     12,288 B
  unsigned short* QKV  = (unsigned short*)(ws + 23080960);    // 8192*3072*2  = 50,331,648 B

  ln_kernel<<<8192, 256, 0, stream>>>(inp, gamma, beta, Xln);
  wtrans_kernel<<<dim3(32, 32, 3), 256, 0, stream>>>(Wq, Wk, Wv, Wt);
  biascat_kernel<<<12, 256, 0, stream>>>(bq, bk, bv, bc);
  gemm_kernel<<<dim3(64, 24), 256, 0, stream>>>(Xln, Wt, bc, QKV);
  attn_kernel<<<2048, 256, 0, stream>>>(QKV, inp, out);
}